// Round 6
// baseline (60.973 us; speedup 1.0000x reference)
//
#include <hip/hip_runtime.h>

#define N 256
#define NN 65536

typedef __attribute__((ext_vector_type(8))) __bf16 bf16x8;
typedef __attribute__((ext_vector_type(4))) __bf16 bf16x4v;
typedef __attribute__((ext_vector_type(4))) float f32x4;

// ---- workspace layout (float offsets) ----
#define F_PART   0u         // [256 blocks][256 b][32 ml] yadj partials
#define F_SPART  2097152u   // [8 mt][256 b][256 n] s_adj partials
#define F_WSC    2621440u   // [256] colsum(W)+strided colsum(cl_bias)
#define F_SFULL  2621696u   // [65536]
#define F_YADJ   2687232u   // [65536]
#define WS_FLOATS 2752768u

static __device__ __forceinline__ f32x4 mfma16(bf16x8 a, bf16x8 b, f32x4 c) {
  return __builtin_amdgcn_mfma_f32_16x16x32_bf16(a, b, c, 0, 0, 0);
}
static __device__ __forceinline__ bf16x4v pack4(float4 v) {
  bf16x4v r;
  r[0] = (__bf16)v.x; r[1] = (__bf16)v.y; r[2] = (__bf16)v.z; r[3] = (__bf16)v.w;
  return r;
}
static __device__ __forceinline__ bf16x8 pack8(float4 a, float4 b) {
  bf16x8 r;
  r[0] = (__bf16)a.x; r[1] = (__bf16)a.y; r[2] = (__bf16)a.z; r[3] = (__bf16)a.w;
  r[4] = (__bf16)b.x; r[5] = (__bf16)b.y; r[6] = (__bf16)b.z; r[7] = (__bf16)b.w;
  return r;
}

typedef __attribute__((address_space(1))) const unsigned int ga_u32;
typedef __attribute__((address_space(3))) unsigned int ls_u32;
static __device__ __forceinline__ void gload16(const void* g, void* l) {
  __builtin_amdgcn_global_load_lds((ga_u32*)g, (ls_u32*)l, 16, 0, 0);
}

// counted-vmcnt barrier (T4): tiles stay in flight across it
#define BARV(NV)                                                          \
  asm volatile("s_waitcnt vmcnt(" #NV ") lgkmcnt(0)" ::: "memory");       \
  __builtin_amdgcn_s_barrier();                                           \
  __builtin_amdgcn_sched_barrier(0);
// LDS-only barrier (between compute and re-staging a buffer)
#define BARL()                                                            \
  asm volatile("s_waitcnt lgkmcnt(0)" ::: "memory");                      \
  __builtin_amdgcn_s_barrier();                                           \
  __builtin_amdgcn_sched_barrier(0);

// ============================================================================
// kbig v5: grid 256 = 8 mt x 32 s; 512 thr (8 waves x 32 b-rows).
//   clw tiles staged as RAW F32 via global_load_lds DMA (no VGPR staging ->
//   compiler cannot sink the loads; vmcnt counts them exactly). 4 rotating
//   32KB LDS buffers, 3 tiles in flight at steady state, waits are counted
//   vmcnt(12/8/4/0) - never a mid-loop drain. f32->bf16 conversion happens
//   at fragment-build (2x ds_read_b128 + pack). Swizzle done by pre-XORing
//   the per-lane GLOBAL source address; read applies the same XOR (involution).
//   Each wave stages rows w*4..w*4+3 of each tile (4 x global_load_lds).
// LDS: 4 bufs x 32KB @0 | xl[8][256]f32 @131072 (wsc red reuses) |
//      sred[8][256]f32 @139264  (147456 B total -> 1 block/CU)
// ============================================================================
__global__ void __launch_bounds__(512) kbig(
    const float* __restrict__ X, const float* __restrict__ ctx,
    const float* __restrict__ W, const float* __restrict__ clb,
    const float* __restrict__ clw, float* __restrict__ ws)
{
  extern __shared__ char smem[];
  float* xl   = (float*)(smem + 131072);
  float* sred = (float*)(smem + 139264);
  float* red  = (float*)(smem + 131072);  // reuses xl post-loop
  const int t = threadIdx.x;
  const int mt = blockIdx.x >> 5, s = blockIdx.x & 31;
  const int n0 = s * 8, m0g = mt * 32;

  const int lane = t & 63, w = t >> 6;
  const int wb = w * 32, l15 = lane & 15, lhi = lane >> 4;
  const int sw2 = (l15 & 7) << 4;

  // ---- prologue: consume ctx->af and X->xl FULLY, then pin with
  // sched_barrier so no compiler waitcnt drifts into the DMA pipeline ----
  bf16x8 af[2][8];
#pragma unroll
  for (int i = 0; i < 2; ++i)
#pragma unroll
    for (int c = 0; c < 8; ++c) {
      const float4* p =
          (const float4*)(ctx + (wb + i * 16 + l15) * N + c * 32 + lhi * 8);
      af[i][c] = pack8(p[0], p[1]);
    }
  if (t < 256) {  // xl[nn][b] = X[b, n0+nn]
    const float4* xp = (const float4*)(X + t * N + n0);
    const float4 x0 = xp[0], x1 = xp[1];
    xl[0 * 256 + t] = x0.x; xl[1 * 256 + t] = x0.y;
    xl[2 * 256 + t] = x0.z; xl[3 * 256 + t] = x0.w;
    xl[4 * 256 + t] = x1.x; xl[5 * 256 + t] = x1.y;
    xl[6 * 256 + t] = x1.z; xl[7 * 256 + t] = x1.w;
  }
  __builtin_amdgcn_sched_barrier(0);  // all compiler vm loads retired above

  // ---- DMA staging: wave w stages tile rows w*4..w*4+3 (1KB each) ----
#define ISSUE_T(TT, BUFI)                                                   \
  {                                                                         \
    _Pragma("unroll")                                                       \
    for (int i = 0; i < 4; ++i) {                                           \
      const int rowl = w * 4 + i;                                           \
      const size_t grow = (size_t)((m0g + rowl) * 256 + n0 + (TT));         \
      gload16((const char*)clw + grow * 1024 +                              \
                  (size_t)((lane * 16) ^ ((rowl & 7) << 4)),                \
              smem + (BUFI) * 32768 + rowl * 1024);                         \
    }                                                                       \
  }

  const f32x4 zero = {0.f, 0.f, 0.f, 0.f};
  f32x4 acc[2][2];
  acc[0][0] = zero; acc[0][1] = zero; acc[1][0] = zero; acc[1][1] = zero;

#define COMP(NNV)                                                           \
  {                                                                         \
    const char* buf = smem + ((NNV) & 3) * 32768;                           \
    f32x4 h[2][2];                                                          \
    h[0][0] = zero; h[0][1] = zero; h[1][0] = zero; h[1][1] = zero;         \
    _Pragma("unroll")                                                       \
    for (int c = 0; c < 8; ++c) {                                           \
      const int colb = c * 128 + lhi * 32;                                  \
      const float4 p00 = *(const float4*)(buf + l15 * 1024 + (colb ^ sw2)); \
      const float4 p01 =                                                    \
          *(const float4*)(buf + l15 * 1024 + ((colb + 16) ^ sw2));         \
      const float4 p10 =                                                    \
          *(const float4*)(buf + (16 + l15) * 1024 + (colb ^ sw2));         \
      const float4 p11 =                                                    \
          *(const float4*)(buf + (16 + l15) * 1024 + ((colb + 16) ^ sw2));  \
      const bf16x8 b0 = pack8(p00, p01);                                    \
      const bf16x8 b1 = pack8(p10, p11);                                    \
      h[0][0] = mfma16(af[0][c], b0, h[0][0]);                              \
      h[0][1] = mfma16(af[0][c], b1, h[0][1]);                              \
      h[1][0] = mfma16(af[1][c], b0, h[1][0]);                              \
      h[1][1] = mfma16(af[1][c], b1, h[1][1]);                              \
    }                                                                       \
    _Pragma("unroll")                                                       \
    for (int fb = 0; fb < 2; ++fb) {                                        \
      _Pragma("unroll")                                                     \
      for (int r = 0; r < 4; ++r) {                                         \
        const int brow = wb + fb * 16 + lhi * 4 + r;                        \
        const float xv = xl[(NNV) * 256 + brow];                            \
        acc[fb][0][r] += xv * h[fb][0][r];                                  \
        acc[fb][1][r] += xv * h[fb][1][r];                                  \
        float v = h[fb][0][r] + h[fb][1][r];                                \
        v += __shfl_xor(v, 1); v += __shfl_xor(v, 2);                       \
        v += __shfl_xor(v, 4); v += __shfl_xor(v, 8);                       \
        if (l15 == 0) sred[(NNV) * 256 + brow] = v;                         \
      }                                                                     \
    }                                                                       \
  }

  // pipeline: 4 tiles issued up front; steady state keeps 3-4 in flight
  ISSUE_T(0, 0) ISSUE_T(1, 1) ISSUE_T(2, 2) ISSUE_T(3, 3)  // out = 16
  BARV(12)                       // tile 0 landed (own 4 oldest retired)
  COMP(0) BARL() ISSUE_T(4, 0)   // out = 16 (t1,t2,t3,t4)
  BARV(12)                       // tile 1
  COMP(1) BARL() ISSUE_T(5, 1)
  BARV(12)                       // tile 2
  COMP(2) BARL() ISSUE_T(6, 2)
  BARV(12)                       // tile 3
  COMP(3) BARL() ISSUE_T(7, 3)
  BARV(12)                       // tile 4
  COMP(4) BARL()
  BARV(8)                        // tile 5
  COMP(5) BARL()
  BARV(4)                        // tile 6
  COMP(6) BARL()
  BARV(0)                        // tile 7
  COMP(7)
#undef ISSUE_T
#undef COMP

  // yadj partials: [block][b][32 ml] (coalesced)
  const int base = blockIdx.x * 8192;
#pragma unroll
  for (int fb = 0; fb < 2; ++fb)
#pragma unroll
    for (int fm = 0; fm < 2; ++fm)
#pragma unroll
      for (int r = 0; r < 4; ++r)
        ws[F_PART + base + (wb + fb * 16 + lhi * 4 + r) * 32 + fm * 16 + l15] =
            acc[fb][fm][r];

  // s_adj partials from sred (same-wave rows): float4 of 4 n per lane
  {
    const int b = wb + (lane >> 1);
    const int nh = (lane & 1) * 4;
    float4 v;
    v.x = sred[(nh + 0) * 256 + b];
    v.y = sred[(nh + 1) * 256 + b];
    v.z = sred[(nh + 2) * 256 + b];
    v.w = sred[(nh + 3) * 256 + b];
    *(float4*)(ws + F_SPART + mt * NN + b * N + n0 + nh) = v;
  }

  // wsc: colsum of W+CB for 8 j-columns, by mt==0 blocks (red reuses xl)
  if (mt == 0) {
    __syncthreads();
    if (t < 256) {
      const float4* wp = (const float4*)(W + t * N + s * 8);
      const float4* cp = (const float4*)(clb + t * N + s * 8);
      const float4 a0 = wp[0], a1 = wp[1], b0 = cp[0], b1 = cp[1];
      red[0 * 256 + t] = a0.x + b0.x; red[1 * 256 + t] = a0.y + b0.y;
      red[2 * 256 + t] = a0.z + b0.z; red[3 * 256 + t] = a0.w + b0.w;
      red[4 * 256 + t] = a1.x + b1.x; red[5 * 256 + t] = a1.y + b1.y;
      red[6 * 256 + t] = a1.z + b1.z; red[7 * 256 + t] = a1.w + b1.w;
    }
    __syncthreads();
    if (t < 64) {
      const int jj = t >> 3, seg = t & 7;
      float v = 0.f;
#pragma unroll
      for (int i = 0; i < 32; ++i) v += red[jj * 256 + seg * 32 + i];
      v += __shfl_xor(v, 1);
      v += __shfl_xor(v, 2);
      v += __shfl_xor(v, 4);
      if (seg == 0) ws[F_WSC + s * 8 + jj] = v;
    }
  }
}

// ============================================================================
// kred: yadj = sum_s partials; s_full = wsc + sum_mt spart
// ============================================================================
__global__ void __launch_bounds__(256) kred(float* __restrict__ ws)
{
  const int o = blockIdx.x * 256 + threadIdx.x;
  const int b = o >> 8, col = o & 255;
  const int mt = col >> 5, ml = col & 31;
  float y = 0.f;
#pragma unroll
  for (int si = 0; si < 32; ++si)
    y += ws[F_PART + ((mt * 32 + si) * 256 + b) * 32 + ml];
  ws[F_YADJ + o] = y;
  float sv = ws[F_WSC + col];
#pragma unroll
  for (int q = 0; q < 8; ++q)
    sv += ws[F_SPART + q * NN + o];
  ws[F_SFULL + o] = sv;
}

// ============================================================================
// kfin: 64 blocks (32b x 32k tiles), 256 thr (4 waves, one 16x16 quadrant each)
//   d = s_full @ A  and  wx = X @ (W+CB)^T   (two fused K=256 MFMA chains)
//   out = scale*(X*d - wx - yadj);  out2 = ctx*t/(t+1) + X/(t+1)
// LDS: S@0 | XT@16384 | AT@32768 | WCB@49152 (16KB each)
// ============================================================================
__global__ void __launch_bounds__(256) kfin(
    const float* __restrict__ X, const float* __restrict__ ctx,
    const float* __restrict__ W, const float* __restrict__ clb,
    const float* __restrict__ A, const float* __restrict__ scale,
    const int* __restrict__ tptr, float* __restrict__ out,
    float* __restrict__ ws)
{
  extern __shared__ char smem[];
  const int t = threadIdx.x, blk = blockIdx.x;
  const int b0 = (blk >> 3) * 32, k0 = (blk & 7) * 32;
  {
    const int row = t >> 3, q = t & 7;
    const int sw = (row & 7) << 4;
    const float4* sp = (const float4*)(ws + F_SFULL + (b0 + row) * N);
    const float4* xp = (const float4*)(X + (b0 + row) * N);
    const float4* wp = (const float4*)(W + (k0 + row) * N);
    const float4* cp = (const float4*)(clb + (k0 + row) * N);
#pragma unroll
    for (int i = 0; i < 8; ++i) {
      const int f4 = q * 8 + i;
      const int off = row * 512 + ((f4 * 8) ^ sw);
      *(bf16x4v*)(smem + off) = pack4(sp[f4]);
      *(bf16x4v*)(smem + 16384 + off) = pack4(xp[f4]);
      const float4 wv = wp[f4], cv = cp[f4];
      float4 s2;
      s2.x = wv.x + cv.x; s2.y = wv.y + cv.y;
      s2.z = wv.z + cv.z; s2.w = wv.w + cv.w;
      *(bf16x4v*)(smem + 49152 + off) = pack4(s2);
    }
    // AT[kk][j] = A[j][k0+kk]
    const float4* ap = (const float4*)(A + t * N + k0);
    char* at = smem + 32768;
#pragma unroll
    for (int i = 0; i < 8; ++i) {
      const float4 v = ap[i];
      const int kk = i * 4;
      *(__bf16*)(at + (kk + 0) * 512 + ((t * 2) ^ (((kk + 0) & 7) << 4))) = (__bf16)v.x;
      *(__bf16*)(at + (kk + 1) * 512 + ((t * 2) ^ (((kk + 1) & 7) << 4))) = (__bf16)v.y;
      *(__bf16*)(at + (kk + 2) * 512 + ((t * 2) ^ (((kk + 2) & 7) << 4))) = (__bf16)v.z;
      *(__bf16*)(at + (kk + 3) * 512 + ((t * 2) ^ (((kk + 3) & 7) << 4))) = (__bf16)v.w;
    }
  }
  __syncthreads();
  const int lane = t & 63, w = t >> 6;
  const int l15 = lane & 15, lhi = lane >> 4;
  const int wqb = (w >> 1) * 16, wqk = (w & 1) * 16;
  const int swz = (l15 & 7) << 4;
  f32x4 accd = {0.f, 0.f, 0.f, 0.f}, accw = {0.f, 0.f, 0.f, 0.f};
#pragma unroll
  for (int c = 0; c < 8; ++c) {
    const int kb = c * 64 + lhi * 16;
    bf16x8 as  = *(const bf16x8*)(smem + (wqb + l15) * 512 + (kb ^ swz));
    bf16x8 aat = *(const bf16x8*)(smem + 32768 + (wqk + l15) * 512 + (kb ^ swz));
    bf16x8 ax  = *(const bf16x8*)(smem + 16384 + (wqb + l15) * 512 + (kb ^ swz));
    bf16x8 awc = *(const bf16x8*)(smem + 49152 + (wqk + l15) * 512 + (kb ^ swz));
    accd = mfma16(as, aat, accd);
    accw = mfma16(ax, awc, accw);
  }
  const float sc = scale[0];
  const float tf = (float)(*tptr);
  const float c1 = tf / (tf + 1.f), c2 = 1.f / (tf + 1.f);
#pragma unroll
  for (int r = 0; r < 4; ++r) {
    const int b = b0 + wqb + lhi * 4 + r, k = k0 + wqk + l15;
    const int idx = b * N + k;
    const float xv = X[idx];
    out[idx] = sc * (xv * accd[r] - accw[r] - ws[F_YADJ + idx]);
    out[NN + idx] = ctx[idx] * c1 + xv * c2;
  }
}

extern "C" void kernel_launch(void* const* d_in, const int* in_sizes, int n_in,
                              void* d_out, int out_size, void* d_ws, size_t ws_size,
                              hipStream_t stream)
{
  (void)in_sizes; (void)n_in; (void)out_size;
  const float* X     = (const float*)d_in[0];
  const float* ctx   = (const float*)d_in[1];
  const float* W     = (const float*)d_in[2];
  const float* scale = (const float*)d_in[3];
  const float* A     = (const float*)d_in[4];
  const float* clw   = (const float*)d_in[5];
  const float* clb   = (const float*)d_in[6];
  const int*   tptr  = (const int*)d_in[7];
  float* out = (float*)d_out;
  float* ws  = (float*)d_ws;

  if (ws_size < (size_t)WS_FLOATS * sizeof(float)) return;

  (void)hipFuncSetAttribute((const void*)kbig,
                            hipFuncAttributeMaxDynamicSharedMemorySize, 147456);
  (void)hipFuncSetAttribute((const void*)kfin,
                            hipFuncAttributeMaxDynamicSharedMemorySize, 65536);

  kbig<<<256, 512, 147456, stream>>>(X, ctx, W, clb, clw, ws);
  kred<<<256, 256, 0, stream>>>(ws);
  kfin<<<64, 256, 65536, stream>>>(X, ctx, W, clb, A, scale, tptr, out, ws);
}

// Round 7
// 58.945 us; speedup vs baseline: 1.0344x; 1.0344x over previous
//
#include <hip/hip_runtime.h>

#define N 256
#define NN 65536

typedef __attribute__((ext_vector_type(8))) __bf16 bf16x8;
typedef __attribute__((ext_vector_type(4))) __bf16 bf16x4v;
typedef __attribute__((ext_vector_type(4))) float f32x4;

// ---- workspace layout (float offsets) ----
#define F_PART   0u         // [512 blocks][128 bl][32 ml] yadj partials
#define F_SPART  2097152u   // [8 mt][256 b][256 n] s_adj partials
#define F_WSC    2621440u   // [256]
#define F_SFULL  2621696u   // [65536]
#define F_YADJ   2687232u   // [65536]
#define WS_FLOATS 2752768u

static __device__ __forceinline__ f32x4 mfma16(bf16x8 a, bf16x8 b, f32x4 c) {
  return __builtin_amdgcn_mfma_f32_16x16x32_bf16(a, b, c, 0, 0, 0);
}
static __device__ __forceinline__ bf16x4v pack4(float4 v) {
  bf16x4v r;
  r[0] = (__bf16)v.x; r[1] = (__bf16)v.y; r[2] = (__bf16)v.z; r[3] = (__bf16)v.w;
  return r;
}
static __device__ __forceinline__ bf16x8 pack8(float4 a, float4 b) {
  bf16x8 r;
  r[0] = (__bf16)a.x; r[1] = (__bf16)a.y; r[2] = (__bf16)a.z; r[3] = (__bf16)a.w;
  r[4] = (__bf16)b.x; r[5] = (__bf16)b.y; r[6] = (__bf16)b.z; r[7] = (__bf16)b.w;
  return r;
}

typedef __attribute__((address_space(1))) const unsigned int ga_u32;
typedef __attribute__((address_space(3))) unsigned int ls_u32;
static __device__ __forceinline__ void gload16(const void* g, void* l) {
  __builtin_amdgcn_global_load_lds((ga_u32*)g, (ls_u32*)l, 16, 0, 0);
}

#define BARV(NV)                                                          \
  asm volatile("s_waitcnt vmcnt(" #NV ") lgkmcnt(0)" ::: "memory");       \
  __builtin_amdgcn_s_barrier();                                           \
  __builtin_amdgcn_sched_barrier(0);
#define BARL()                                                            \
  asm volatile("s_waitcnt lgkmcnt(0)" ::: "memory");                      \
  __builtin_amdgcn_s_barrier();                                           \
  __builtin_amdgcn_sched_barrier(0);

// ============================================================================
// kbig v7: OCCUPANCY EXPERIMENT. grid 512 = 2 bh x 8 mt x 32 s; 256 thr
//   (4 waves x 32 b-rows, b-range 128 per block). LDS 72KB -> 2 independent
//   blocks/CU (vs 1 mega-block before): co-resident blocks overlap each
//   other's barriers/latency (m114). clw read 2x chip-wide; twin blocks
//   (x, x+256) land on the same XCD -> twin stream is L2/L3-resident.
//   Staging = R6's DMA global_load_lds (f32, unsinkable, 0 VGPR) with
//   counted vmcnt, depth-2 double buffer (16 loads in flight, BARV(8)).
// LDS: 2 bufs x 32KB @0 | xl[8][128]f32 @65536 | sred[8][128]f32 @69632
//      (73728 B total; wsc red 8KB reuses tile region post-loop)
// ============================================================================
__global__ void __launch_bounds__(256, 2) kbig(
    const float* __restrict__ X, const float* __restrict__ ctx,
    const float* __restrict__ W, const float* __restrict__ clb,
    const float* __restrict__ clw, float* __restrict__ ws)
{
  extern __shared__ char smem[];
  float* xl   = (float*)(smem + 65536);
  float* sred = (float*)(smem + 69632);
  float* red  = (float*)smem;  // reuses tile region post-loop
  const int t = threadIdx.x;
  const int bh = blockIdx.x >> 8;
  const int rem = blockIdx.x & 255;
  const int mt = rem >> 5, s = rem & 31;
  const int n0 = s * 8, m0g = mt * 32, b0g = bh * 128;

  const int lane = t & 63, w = t >> 6;
  const int wb = w * 32;              // local b-base of this wave (0..96)
  const int l15 = lane & 15, lhi = lane >> 4;
  const int sw2 = (l15 & 7) << 4;

  // ---- prologue: ctx->af (A-frags, 32 local b-rows/wave) and X->xl ----
  bf16x8 af[2][8];
#pragma unroll
  for (int i = 0; i < 2; ++i)
#pragma unroll
    for (int c = 0; c < 8; ++c) {
      const float4* p = (const float4*)(ctx + (b0g + wb + i * 16 + l15) * N +
                                        c * 32 + lhi * 8);
      af[i][c] = pack8(p[0], p[1]);
    }
  if (t < 128) {  // xl[nn][bl] = X[b0g+bl, n0+nn]
    const float4* xp = (const float4*)(X + (b0g + t) * N + n0);
    const float4 x0 = xp[0], x1 = xp[1];
    xl[0 * 128 + t] = x0.x; xl[1 * 128 + t] = x0.y;
    xl[2 * 128 + t] = x0.z; xl[3 * 128 + t] = x0.w;
    xl[4 * 128 + t] = x1.x; xl[5 * 128 + t] = x1.y;
    xl[6 * 128 + t] = x1.z; xl[7 * 128 + t] = x1.w;
  }
  __builtin_amdgcn_sched_barrier(0);  // compiler vm loads retired above

  // ---- DMA staging: wave w stages tile rows w*8..w*8+7 (1KB each) ----
#define ISSUE_T(TT, BUFI)                                                   \
  {                                                                         \
    _Pragma("unroll")                                                       \
    for (int i = 0; i < 8; ++i) {                                           \
      const int rowl = w * 8 + i;                                           \
      const size_t grow = (size_t)((m0g + rowl) * 256 + n0 + (TT));         \
      gload16((const char*)clw + grow * 1024 +                              \
                  (size_t)((lane * 16) ^ ((rowl & 7) << 4)),                \
              smem + (BUFI) * 32768 + rowl * 1024);                         \
    }                                                                       \
  }

  const f32x4 zero = {0.f, 0.f, 0.f, 0.f};
  f32x4 acc[2][2];
  acc[0][0] = zero; acc[0][1] = zero; acc[1][0] = zero; acc[1][1] = zero;

#define COMP(NNV)                                                           \
  {                                                                         \
    const char* buf = smem + ((NNV) & 1) * 32768;                           \
    f32x4 h[2][2];                                                          \
    h[0][0] = zero; h[0][1] = zero; h[1][0] = zero; h[1][1] = zero;         \
    _Pragma("unroll")                                                       \
    for (int c = 0; c < 8; ++c) {                                           \
      const int colb = c * 128 + lhi * 32;                                  \
      const float4 p00 = *(const float4*)(buf + l15 * 1024 + (colb ^ sw2)); \
      const float4 p01 =                                                    \
          *(const float4*)(buf + l15 * 1024 + ((colb + 16) ^ sw2));         \
      const float4 p10 =                                                    \
          *(const float4*)(buf + (16 + l15) * 1024 + (colb ^ sw2));         \
      const float4 p11 =                                                    \
          *(const float4*)(buf + (16 + l15) * 1024 + ((colb + 16) ^ sw2));  \
      const bf16x8 b0 = pack8(p00, p01);                                    \
      const bf16x8 b1 = pack8(p10, p11);                                    \
      h[0][0] = mfma16(af[0][c], b0, h[0][0]);                              \
      h[0][1] = mfma16(af[0][c], b1, h[0][1]);                              \
      h[1][0] = mfma16(af[1][c], b0, h[1][0]);                              \
      h[1][1] = mfma16(af[1][c], b1, h[1][1]);                              \
    }                                                                       \
    _Pragma("unroll")                                                       \
    for (int fb = 0; fb < 2; ++fb) {                                        \
      _Pragma("unroll")                                                     \
      for (int r = 0; r < 4; ++r) {                                         \
        const int brow = wb + fb * 16 + lhi * 4 + r;                        \
        const float xv = xl[(NNV) * 128 + brow];                            \
        acc[fb][0][r] += xv * h[fb][0][r];                                  \
        acc[fb][1][r] += xv * h[fb][1][r];                                  \
        float v = h[fb][0][r] + h[fb][1][r];                                \
        v += __shfl_xor(v, 1); v += __shfl_xor(v, 2);                       \
        v += __shfl_xor(v, 4); v += __shfl_xor(v, 8);                       \
        if (l15 == 0) sred[(NNV) * 128 + brow] = v;                         \
      }                                                                     \
    }                                                                       \
  }

  // depth-2 pipeline, counted vmcnt(8) (own-wave: 8 loads/tile)
  ISSUE_T(0, 0) ISSUE_T(1, 1)
  BARV(8)
  COMP(0) BARL() ISSUE_T(2, 0)
  BARV(8)
  COMP(1) BARL() ISSUE_T(3, 1)
  BARV(8)
  COMP(2) BARL() ISSUE_T(4, 0)
  BARV(8)
  COMP(3) BARL() ISSUE_T(5, 1)
  BARV(8)
  COMP(4) BARL() ISSUE_T(6, 0)
  BARV(8)
  COMP(5) BARL() ISSUE_T(7, 1)
  BARV(8)
  COMP(6) BARL()
  BARV(0)
  COMP(7)
#undef ISSUE_T
#undef COMP

  // yadj partials: [block][128 bl][32 ml]
  const int base = blockIdx.x * 4096;
#pragma unroll
  for (int fb = 0; fb < 2; ++fb)
#pragma unroll
    for (int fm = 0; fm < 2; ++fm)
#pragma unroll
      for (int r = 0; r < 4; ++r)
        ws[F_PART + base + (wb + fb * 16 + lhi * 4 + r) * 32 + fm * 16 + l15] =
            acc[fb][fm][r];

  // s_adj partials: wave covers its 32 local b-rows, float4 of 4 n per lane
  {
    const int bl = wb + (lane >> 1);
    const int nh = (lane & 1) * 4;
    float4 v;
    v.x = sred[(nh + 0) * 128 + bl];
    v.y = sred[(nh + 1) * 128 + bl];
    v.z = sred[(nh + 2) * 128 + bl];
    v.w = sred[(nh + 3) * 128 + bl];
    *(float4*)(ws + F_SPART + mt * NN + (b0g + bl) * N + n0 + nh) = v;
  }

  // wsc: colsum of W+CB for 8 j-columns, by (mt==0,bh==0) blocks
  if (mt == 0 && bh == 0) {
    __syncthreads();
    const float4* wp = (const float4*)(W + t * N + s * 8);
    const float4* cp = (const float4*)(clb + t * N + s * 8);
    const float4 a0 = wp[0], a1 = wp[1], c0 = cp[0], c1 = cp[1];
    red[0 * 256 + t] = a0.x + c0.x; red[1 * 256 + t] = a0.y + c0.y;
    red[2 * 256 + t] = a0.z + c0.z; red[3 * 256 + t] = a0.w + c0.w;
    red[4 * 256 + t] = a1.x + c1.x; red[5 * 256 + t] = a1.y + c1.y;
    red[6 * 256 + t] = a1.z + c1.z; red[7 * 256 + t] = a1.w + c1.w;
    __syncthreads();
    if (t < 64) {
      const int jj = t >> 3, seg = t & 7;
      float v = 0.f;
#pragma unroll
      for (int i = 0; i < 32; ++i) v += red[jj * 256 + seg * 32 + i];
      v += __shfl_xor(v, 1);
      v += __shfl_xor(v, 2);
      v += __shfl_xor(v, 4);
      if (seg == 0) ws[F_WSC + s * 8 + jj] = v;
    }
  }
}

// ============================================================================
// kred: yadj = sum over 32 s-chunks (per bh); s_full = wsc + sum_mt spart
// ============================================================================
__global__ void __launch_bounds__(256) kred(float* __restrict__ ws)
{
  const int o = blockIdx.x * 256 + threadIdx.x;
  const int b = o >> 8, col = o & 255;
  const int mt = col >> 5, ml = col & 31;
  const int bhh = b >> 7, bl = b & 127;
  float y = 0.f;
#pragma unroll
  for (int si = 0; si < 32; ++si)
    y += ws[F_PART + (bhh * 256 + mt * 32 + si) * 4096 + bl * 32 + ml];
  ws[F_YADJ + o] = y;
  float sv = ws[F_WSC + col];
#pragma unroll
  for (int q = 0; q < 8; ++q)
    sv += ws[F_SPART + q * NN + o];
  ws[F_SFULL + o] = sv;
}

// ============================================================================
// kfin: unchanged (64 blocks, 2 fused K=256 MFMA chains + epilogue)
// ============================================================================
__global__ void __launch_bounds__(256) kfin(
    const float* __restrict__ X, const float* __restrict__ ctx,
    const float* __restrict__ W, const float* __restrict__ clb,
    const float* __restrict__ A, const float* __restrict__ scale,
    const int* __restrict__ tptr, float* __restrict__ out,
    float* __restrict__ ws)
{
  extern __shared__ char smem[];
  const int t = threadIdx.x, blk = blockIdx.x;
  const int b0 = (blk >> 3) * 32, k0 = (blk & 7) * 32;
  {
    const int row = t >> 3, q = t & 7;
    const int sw = (row & 7) << 4;
    const float4* sp = (const float4*)(ws + F_SFULL + (b0 + row) * N);
    const float4* xp = (const float4*)(X + (b0 + row) * N);
    const float4* wp = (const float4*)(W + (k0 + row) * N);
    const float4* cp = (const float4*)(clb + (k0 + row) * N);
#pragma unroll
    for (int i = 0; i < 8; ++i) {
      const int f4 = q * 8 + i;
      const int off = row * 512 + ((f4 * 8) ^ sw);
      *(bf16x4v*)(smem + off) = pack4(sp[f4]);
      *(bf16x4v*)(smem + 16384 + off) = pack4(xp[f4]);
      const float4 wv = wp[f4], cv = cp[f4];
      float4 s2;
      s2.x = wv.x + cv.x; s2.y = wv.y + cv.y;
      s2.z = wv.z + cv.z; s2.w = wv.w + cv.w;
      *(bf16x4v*)(smem + 49152 + off) = pack4(s2);
    }
    const float4* ap = (const float4*)(A + t * N + k0);
    char* at = smem + 32768;
#pragma unroll
    for (int i = 0; i < 8; ++i) {
      const float4 v = ap[i];
      const int kk = i * 4;
      *(__bf16*)(at + (kk + 0) * 512 + ((t * 2) ^ (((kk + 0) & 7) << 4))) = (__bf16)v.x;
      *(__bf16*)(at + (kk + 1) * 512 + ((t * 2) ^ (((kk + 1) & 7) << 4))) = (__bf16)v.y;
      *(__bf16*)(at + (kk + 2) * 512 + ((t * 2) ^ (((kk + 2) & 7) << 4))) = (__bf16)v.z;
      *(__bf16*)(at + (kk + 3) * 512 + ((t * 2) ^ (((kk + 3) & 7) << 4))) = (__bf16)v.w;
    }
  }
  __syncthreads();
  const int lane = t & 63, w = t >> 6;
  const int l15 = lane & 15, lhi = lane >> 4;
  const int wqb = (w >> 1) * 16, wqk = (w & 1) * 16;
  const int swz = (l15 & 7) << 4;
  f32x4 accd = {0.f, 0.f, 0.f, 0.f}, accw = {0.f, 0.f, 0.f, 0.f};
#pragma unroll
  for (int c = 0; c < 8; ++c) {
    const int kb = c * 64 + lhi * 16;
    bf16x8 as  = *(const bf16x8*)(smem + (wqb + l15) * 512 + (kb ^ swz));
    bf16x8 aat = *(const bf16x8*)(smem + 32768 + (wqk + l15) * 512 + (kb ^ swz));
    bf16x8 ax  = *(const bf16x8*)(smem + 16384 + (wqb + l15) * 512 + (kb ^ swz));
    bf16x8 awc = *(const bf16x8*)(smem + 49152 + (wqk + l15) * 512 + (kb ^ swz));
    accd = mfma16(as, aat, accd);
    accw = mfma16(ax, awc, accw);
  }
  const float sc = scale[0];
  const float tf = (float)(*tptr);
  const float c1 = tf / (tf + 1.f), c2 = 1.f / (tf + 1.f);
#pragma unroll
  for (int r = 0; r < 4; ++r) {
    const int b = b0 + wqb + lhi * 4 + r, k = k0 + wqk + l15;
    const int idx = b * N + k;
    const float xv = X[idx];
    out[idx] = sc * (xv * accd[r] - accw[r] - ws[F_YADJ + idx]);
    out[NN + idx] = ctx[idx] * c1 + xv * c2;
  }
}

extern "C" void kernel_launch(void* const* d_in, const int* in_sizes, int n_in,
                              void* d_out, int out_size, void* d_ws, size_t ws_size,
                              hipStream_t stream)
{
  (void)in_sizes; (void)n_in; (void)out_size;
  const float* X     = (const float*)d_in[0];
  const float* ctx   = (const float*)d_in[1];
  const float* W     = (const float*)d_in[2];
  const float* scale = (const float*)d_in[3];
  const float* A     = (const float*)d_in[4];
  const float* clw   = (const float*)d_in[5];
  const float* clb   = (const float*)d_in[6];
  const int*   tptr  = (const int*)d_in[7];
  float* out = (float*)d_out;
  float* ws  = (float*)d_ws;

  if (ws_size < (size_t)WS_FLOATS * sizeof(float)) return;

  (void)hipFuncSetAttribute((const void*)kbig,
                            hipFuncAttributeMaxDynamicSharedMemorySize, 73728);
  (void)hipFuncSetAttribute((const void*)kfin,
                            hipFuncAttributeMaxDynamicSharedMemorySize, 65536);

  kbig<<<512, 256, 73728, stream>>>(X, ctx, W, clb, clw, ws);
  kred<<<256, 256, 0, stream>>>(ws);
  kfin<<<64, 256, 65536, stream>>>(X, ctx, W, clb, A, scale, tptr, out, ws);
}

// Round 8
// 53.069 us; speedup vs baseline: 1.1489x; 1.1107x over previous
//
#include <hip/hip_runtime.h>

#define N 256
#define NN 65536

typedef __attribute__((ext_vector_type(8))) __bf16 bf16x8;
typedef __attribute__((ext_vector_type(4))) __bf16 bf16x4v;
typedef __attribute__((ext_vector_type(4))) float f32x4;

// ---- workspace layout (float offsets) ----
#define F_PART   0u         // [512 blocks][128 bl][32 ml] yadj partials
#define F_SPART  2097152u   // [8 mt][256 b][256 n] s_adj partials
#define F_WSC    2621440u   // [256]
#define F_SFULL  2621696u   // [65536]
#define F_YADJ   2687232u   // [65536]
#define WS_FLOATS 2752768u

static __device__ __forceinline__ f32x4 mfma16(bf16x8 a, bf16x8 b, f32x4 c) {
  return __builtin_amdgcn_mfma_f32_16x16x32_bf16(a, b, c, 0, 0, 0);
}
static __device__ __forceinline__ bf16x4v pack4(float4 v) {
  bf16x4v r;
  r[0] = (__bf16)v.x; r[1] = (__bf16)v.y; r[2] = (__bf16)v.z; r[3] = (__bf16)v.w;
  return r;
}
static __device__ __forceinline__ bf16x8 pack8(float4 a, float4 b) {
  bf16x8 r;
  r[0] = (__bf16)a.x; r[1] = (__bf16)a.y; r[2] = (__bf16)a.z; r[3] = (__bf16)a.w;
  r[4] = (__bf16)b.x; r[5] = (__bf16)b.y; r[6] = (__bf16)b.z; r[7] = (__bf16)b.w;
  return r;
}

// lgkm-only barrier; vmcnt is managed by the COMPILER's reg-dependence waits
#define BARL()                                                            \
  asm volatile("s_waitcnt lgkmcnt(0)" ::: "memory");                      \
  __builtin_amdgcn_s_barrier();                                           \
  __builtin_amdgcn_sched_barrier(0);

// ============================================================================
// kbig v8: grid 512 = 2 bh x 8 mt x 32 s; 256 thr (4 waves x 32 b-rows).
//   KEY CHANGE: __launch_bounds__(256, 2) -> 256-VGPR budget so the
//   depth-2 register prefetch (rA/rB, 32 VGPRs each) is NOT sunk to its
//   use (every prior round sat at 128 regs with loads sunk = no pipeline).
//   bf16 16KB tiles, 3 rotating LDS buffers, ONE barrier per tile:
//     [ISSUE(t+2)->regs ; WRITE(t+1)<-regs ; BARL ; COMP(t)]
//   The ds_write's reg-dep makes the compiler emit counted vmcnt(8)
//   (tile t+2 stays in flight) - no hand-rolled vmcnt needed.
// LDS: 3 bufs x 16KB @0 | xl[8][128]f32 @49152 | sred[8][128]f32 @53248
//      (57344 B -> 2 blocks/CU; wsc red 8KB reuses buf region post-loop)
// ============================================================================
__global__ void __launch_bounds__(256, 2) kbig(
    const float* __restrict__ X, const float* __restrict__ ctx,
    const float* __restrict__ W, const float* __restrict__ clb,
    const float* __restrict__ clw, float* __restrict__ ws)
{
  extern __shared__ char smem[];
  float* xl   = (float*)(smem + 49152);
  float* sred = (float*)(smem + 53248);
  float* red  = (float*)smem;  // reuses buf region post-loop
  const int t = threadIdx.x;
  const int bh = blockIdx.x >> 8;
  const int rem = blockIdx.x & 255;
  const int mt = rem >> 5, s = rem & 31;
  const int n0 = s * 8, m0g = mt * 32, b0g = bh * 128;

  const int lane = t & 63, w = t >> 6;
  const int wb = w * 32;
  const int l15 = lane & 15, lhi = lane >> 4;
  const int swz = (l15 & 7) << 4;
  const float4* clwf4 = (const float4*)clw;

  // ---- prologue: ctx->af (A-frags), X->xl, then tiles 0,1 into regs ----
  bf16x8 af[2][8];
#pragma unroll
  for (int i = 0; i < 2; ++i)
#pragma unroll
    for (int c = 0; c < 8; ++c) {
      const float4* p = (const float4*)(ctx + (b0g + wb + i * 16 + l15) * N +
                                        c * 32 + lhi * 8);
      af[i][c] = pack8(p[0], p[1]);
    }
  if (t < 128) {  // xl[nn][bl] = X[b0g+bl, n0+nn]
    const float4* xp = (const float4*)(X + (b0g + t) * N + n0);
    const float4 x0 = xp[0], x1 = xp[1];
    xl[0 * 128 + t] = x0.x; xl[1 * 128 + t] = x0.y;
    xl[2 * 128 + t] = x0.z; xl[3 * 128 + t] = x0.w;
    xl[4 * 128 + t] = x1.x; xl[5 * 128 + t] = x1.y;
    xl[6 * 128 + t] = x1.z; xl[7 * 128 + t] = x1.w;
  }

  // wave w owns tile rows w*8..w*8+7; one float4/lane/row
#define ISSUE(TT, R)                                                        \
  _Pragma("unroll")                                                         \
  for (int i = 0; i < 8; ++i) {                                             \
    const int rowl = w * 8 + i;                                             \
    R[i] = clwf4[(size_t)((m0g + rowl) * 256 + n0 + (TT)) * 64 + lane];     \
  }
#define WRITE(TT, R)                                                        \
  _Pragma("unroll")                                                         \
  for (int i = 0; i < 8; ++i) {                                             \
    const int rowl = w * 8 + i;                                             \
    *(bf16x4v*)(smem + ((TT) % 3) * 16384 + rowl * 512 +                    \
                ((lane * 8) ^ ((rowl & 7) << 4))) = pack4(R[i]);            \
  }

  float4 rA[8], rB[8];
  ISSUE(0, rA)
  ISSUE(1, rB)
  __builtin_amdgcn_sched_barrier(0);  // pin load issue before the pipeline

  const f32x4 zero = {0.f, 0.f, 0.f, 0.f};
  f32x4 acc[2][2];
  acc[0][0] = zero; acc[0][1] = zero; acc[1][0] = zero; acc[1][1] = zero;

#define COMP(NNV)                                                           \
  {                                                                         \
    const char* buf = smem + ((NNV) % 3) * 16384;                           \
    f32x4 h[2][2];                                                          \
    h[0][0] = zero; h[0][1] = zero; h[1][0] = zero; h[1][1] = zero;         \
    _Pragma("unroll")                                                       \
    for (int c = 0; c < 8; ++c) {                                           \
      const int kb = c * 64 + lhi * 16;                                     \
      bf16x8 b0 = *(const bf16x8*)(buf + l15 * 512 + (kb ^ swz));           \
      bf16x8 b1 = *(const bf16x8*)(buf + (16 + l15) * 512 + (kb ^ swz));    \
      h[0][0] = mfma16(af[0][c], b0, h[0][0]);                              \
      h[0][1] = mfma16(af[0][c], b1, h[0][1]);                              \
      h[1][0] = mfma16(af[1][c], b0, h[1][0]);                              \
      h[1][1] = mfma16(af[1][c], b1, h[1][1]);                              \
    }                                                                       \
    _Pragma("unroll")                                                       \
    for (int fb = 0; fb < 2; ++fb) {                                        \
      _Pragma("unroll")                                                     \
      for (int r = 0; r < 4; ++r) {                                         \
        const int brow = wb + fb * 16 + lhi * 4 + r;                        \
        const float xv = xl[(NNV) * 128 + brow];                            \
        acc[fb][0][r] += xv * h[fb][0][r];                                  \
        acc[fb][1][r] += xv * h[fb][1][r];                                  \
        float v = h[fb][0][r] + h[fb][1][r];                                \
        v += __shfl_xor(v, 1); v += __shfl_xor(v, 2);                       \
        v += __shfl_xor(v, 4); v += __shfl_xor(v, 8);                       \
        if (l15 == 0) sred[(NNV) * 128 + brow] = v;                         \
      }                                                                     \
    }                                                                       \
  }

  // one barrier per tile; 3 bufs make [COMP(t) || WRITE(t+2)] race-free
  WRITE(0, rA)
  BARL();
  ISSUE(2, rA) __builtin_amdgcn_sched_barrier(0); WRITE(1, rB) BARL(); COMP(0)
  ISSUE(3, rB) __builtin_amdgcn_sched_barrier(0); WRITE(2, rA) BARL(); COMP(1)
  ISSUE(4, rA) __builtin_amdgcn_sched_barrier(0); WRITE(3, rB) BARL(); COMP(2)
  ISSUE(5, rB) __builtin_amdgcn_sched_barrier(0); WRITE(4, rA) BARL(); COMP(3)
  ISSUE(6, rA) __builtin_amdgcn_sched_barrier(0); WRITE(5, rB) BARL(); COMP(4)
  ISSUE(7, rB) __builtin_amdgcn_sched_barrier(0); WRITE(6, rA) BARL(); COMP(5)
  WRITE(7, rB) BARL(); COMP(6)
  COMP(7)
#undef ISSUE
#undef WRITE
#undef COMP

  // yadj partials: [block][128 bl][32 ml]
  const int base = blockIdx.x * 4096;
#pragma unroll
  for (int fb = 0; fb < 2; ++fb)
#pragma unroll
    for (int fm = 0; fm < 2; ++fm)
#pragma unroll
      for (int r = 0; r < 4; ++r)
        ws[F_PART + base + (wb + fb * 16 + lhi * 4 + r) * 32 + fm * 16 + l15] =
            acc[fb][fm][r];

  // s_adj partials: wave covers its 32 local b-rows, float4 of 4 n per lane
  {
    const int bl = wb + (lane >> 1);
    const int nh = (lane & 1) * 4;
    float4 v;
    v.x = sred[(nh + 0) * 128 + bl];
    v.y = sred[(nh + 1) * 128 + bl];
    v.z = sred[(nh + 2) * 128 + bl];
    v.w = sred[(nh + 3) * 128 + bl];
    *(float4*)(ws + F_SPART + mt * NN + (b0g + bl) * N + n0 + nh) = v;
  }

  // wsc: colsum of W+CB for 8 j-columns, by (mt==0,bh==0) blocks
  if (mt == 0 && bh == 0) {
    __syncthreads();
    const float4* wp = (const float4*)(W + t * N + s * 8);
    const float4* cp = (const float4*)(clb + t * N + s * 8);
    const float4 a0 = wp[0], a1 = wp[1], c0 = cp[0], c1 = cp[1];
    red[0 * 256 + t] = a0.x + c0.x; red[1 * 256 + t] = a0.y + c0.y;
    red[2 * 256 + t] = a0.z + c0.z; red[3 * 256 + t] = a0.w + c0.w;
    red[4 * 256 + t] = a1.x + c1.x; red[5 * 256 + t] = a1.y + c1.y;
    red[6 * 256 + t] = a1.z + c1.z; red[7 * 256 + t] = a1.w + c1.w;
    __syncthreads();
    if (t < 64) {
      const int jj = t >> 3, seg = t & 7;
      float v = 0.f;
#pragma unroll
      for (int i = 0; i < 32; ++i) v += red[jj * 256 + seg * 32 + i];
      v += __shfl_xor(v, 1);
      v += __shfl_xor(v, 2);
      v += __shfl_xor(v, 4);
      if (seg == 0) ws[F_WSC + s * 8 + jj] = v;
    }
  }
}

// ============================================================================
// kred: yadj = sum over 32 s-chunks (per bh); s_full = wsc + sum_mt spart
// ============================================================================
__global__ void __launch_bounds__(256) kred(float* __restrict__ ws)
{
  const int o = blockIdx.x * 256 + threadIdx.x;
  const int b = o >> 8, col = o & 255;
  const int mt = col >> 5, ml = col & 31;
  const int bhh = b >> 7, bl = b & 127;
  float y = 0.f;
#pragma unroll
  for (int si = 0; si < 32; ++si)
    y += ws[F_PART + (bhh * 256 + mt * 32 + si) * 4096 + bl * 32 + ml];
  ws[F_YADJ + o] = y;
  float sv = ws[F_WSC + col];
#pragma unroll
  for (int q = 0; q < 8; ++q)
    sv += ws[F_SPART + q * NN + o];
  ws[F_SFULL + o] = sv;
}

// ============================================================================
// kfin: unchanged (64 blocks, 2 fused K=256 MFMA chains + epilogue)
// ============================================================================
__global__ void __launch_bounds__(256) kfin(
    const float* __restrict__ X, const float* __restrict__ ctx,
    const float* __restrict__ W, const float* __restrict__ clb,
    const float* __restrict__ A, const float* __restrict__ scale,
    const int* __restrict__ tptr, float* __restrict__ out,
    float* __restrict__ ws)
{
  extern __shared__ char smem[];
  const int t = threadIdx.x, blk = blockIdx.x;
  const int b0 = (blk >> 3) * 32, k0 = (blk & 7) * 32;
  {
    const int row = t >> 3, q = t & 7;
    const int sw = (row & 7) << 4;
    const float4* sp = (const float4*)(ws + F_SFULL + (b0 + row) * N);
    const float4* xp = (const float4*)(X + (b0 + row) * N);
    const float4* wp = (const float4*)(W + (k0 + row) * N);
    const float4* cp = (const float4*)(clb + (k0 + row) * N);
#pragma unroll
    for (int i = 0; i < 8; ++i) {
      const int f4 = q * 8 + i;
      const int off = row * 512 + ((f4 * 8) ^ sw);
      *(bf16x4v*)(smem + off) = pack4(sp[f4]);
      *(bf16x4v*)(smem + 16384 + off) = pack4(xp[f4]);
      const float4 wv = wp[f4], cv = cp[f4];
      float4 s2;
      s2.x = wv.x + cv.x; s2.y = wv.y + cv.y;
      s2.z = wv.z + cv.z; s2.w = wv.w + cv.w;
      *(bf16x4v*)(smem + 49152 + off) = pack4(s2);
    }
    const float4* ap = (const float4*)(A + t * N + k0);
    char* at = smem + 32768;
#pragma unroll
    for (int i = 0; i < 8; ++i) {
      const float4 v = ap[i];
      const int kk = i * 4;
      *(__bf16*)(at + (kk + 0) * 512 + ((t * 2) ^ (((kk + 0) & 7) << 4))) = (__bf16)v.x;
      *(__bf16*)(at + (kk + 1) * 512 + ((t * 2) ^ (((kk + 1) & 7) << 4))) = (__bf16)v.y;
      *(__bf16*)(at + (kk + 2) * 512 + ((t * 2) ^ (((kk + 2) & 7) << 4))) = (__bf16)v.z;
      *(__bf16*)(at + (kk + 3) * 512 + ((t * 2) ^ (((kk + 3) & 7) << 4))) = (__bf16)v.w;
    }
  }
  __syncthreads();
  const int lane = t & 63, w = t >> 6;
  const int l15 = lane & 15, lhi = lane >> 4;
  const int wqb = (w >> 1) * 16, wqk = (w & 1) * 16;
  const int swz = (l15 & 7) << 4;
  f32x4 accd = {0.f, 0.f, 0.f, 0.f}, accw = {0.f, 0.f, 0.f, 0.f};
#pragma unroll
  for (int c = 0; c < 8; ++c) {
    const int kb = c * 64 + lhi * 16;
    bf16x8 as  = *(const bf16x8*)(smem + (wqb + l15) * 512 + (kb ^ swz));
    bf16x8 aat = *(const bf16x8*)(smem + 32768 + (wqk + l15) * 512 + (kb ^ swz));
    bf16x8 ax  = *(const bf16x8*)(smem + 16384 + (wqb + l15) * 512 + (kb ^ swz));
    bf16x8 awc = *(const bf16x8*)(smem + 49152 + (wqk + l15) * 512 + (kb ^ swz));
    accd = mfma16(as, aat, accd);
    accw = mfma16(ax, awc, accw);
  }
  const float sc = scale[0];
  const float tf = (float)(*tptr);
  const float c1 = tf / (tf + 1.f), c2 = 1.f / (tf + 1.f);
#pragma unroll
  for (int r = 0; r < 4; ++r) {
    const int b = b0 + wqb + lhi * 4 + r, k = k0 + wqk + l15;
    const int idx = b * N + k;
    const float xv = X[idx];
    out[idx] = sc * (xv * accd[r] - accw[r] - ws[F_YADJ + idx]);
    out[NN + idx] = ctx[idx] * c1 + xv * c2;
  }
}

extern "C" void kernel_launch(void* const* d_in, const int* in_sizes, int n_in,
                              void* d_out, int out_size, void* d_ws, size_t ws_size,
                              hipStream_t stream)
{
  (void)in_sizes; (void)n_in; (void)out_size;
  const float* X     = (const float*)d_in[0];
  const float* ctx   = (const float*)d_in[1];
  const float* W     = (const float*)d_in[2];
  const float* scale = (const float*)d_in[3];
  const float* A     = (const float*)d_in[4];
  const float* clw   = (const float*)d_in[5];
  const float* clb   = (const float*)d_in[6];
  const int*   tptr  = (const int*)d_in[7];
  float* out = (float*)d_out;
  float* ws  = (float*)d_ws;

  if (ws_size < (size_t)WS_FLOATS * sizeof(float)) return;

  (void)hipFuncSetAttribute((const void*)kbig,
                            hipFuncAttributeMaxDynamicSharedMemorySize, 57344);
  (void)hipFuncSetAttribute((const void*)kfin,
                            hipFuncAttributeMaxDynamicSharedMemorySize, 65536);

  kbig<<<512, 256, 57344, stream>>>(X, ctx, W, clb, clw, ws);
  kred<<<256, 256, 0, stream>>>(ws);
  kfin<<<64, 256, 65536, stream>>>(X, ctx, W, clb, A, scale, tptr, out, ws);
}